// Round 8
// baseline (146.540 us; speedup 1.0000x reference)
//
#include <hip/hip_runtime.h>
#include <stdint.h>
#include <limits.h>

// ---------------------------------------------------------------------------
// GeToInformedNeighborSampler — round 8 (contention-free witness scan).
//
// Exact clip-aware reduction (validated rounds 5-7, absmax 0):
//   A = max_{j<D} v_j, a = first argmax   (v_j = gumbel(s*NC+j) + logp[j])
//   r[s] = (exists j in [D,NC): v_j > A) ? D-1 : a
//
// Round-7 lesson: the shared wflag was the kernel. ~2800 waves all did an
// AGENT-scope atomic_fetch_or into 25 words = 1-2 cache lines; same-line
// RMWs serialize at the coherence point (~70cy each ~ 60us, VALUBusy 6%).
// Fix: one result slot PER WAVE (wfound[s*WV+wv], always stored, plain
// agent store, 3200 distinct addresses), no flag, no poll, no RMW. A tiny
// reduce kernel ORs the 128 bits per sample. Tail: P(wave needs >k rounds)
// ~ 0.11^k -> max over 3200 waves ~ 4 rounds; hard cap = window (25 rounds).
//
// Per-round best-candidate eval (round 7, kept): evaluate only the round's
// max-bits filter-passer wave-uniformly; fall back to all passers iff it
// fails. Round-level witness-OR is exact either way.
//
// RNG: threefry2x32 key (0,42), classic split, o0-only; raw-bits prune
// filter bits >= kb(A) (conservative, validated rounds 2-7).
// wfound is written unconditionally by its owning wave every call =>
// no stale-state/replay hazard; all handoffs AGENT-scope (G16).
// ---------------------------------------------------------------------------

#define DEVI __device__ __forceinline__

DEVI uint32_t rotl32(uint32_t x, int n) { return (x << n) | (x >> (32 - n)); }

// threefry2x32-20, key (0,42), o0 only. x1 must already include +K1 (=42).
DEVI uint32_t tf_o0p(uint32_t x0, uint32_t x1) {
  const uint32_t K1 = 42u;
  const uint32_t K2 = 0x1BD11BDAu ^ K1;  // K0 = 0
#define TFR(r) x0 += x1; x1 = rotl32(x1, (r)); x1 ^= x0;
  TFR(13) TFR(15) TFR(26) TFR(6)
  x0 += K1; x1 += K2 + 1u;
  TFR(17) TFR(29) TFR(16) TFR(24)
  x0 += K2; x1 += 2u;                    // + K0 + 2
  TFR(13) TFR(15) TFR(26) TFR(6)
  /* x0 += K0 */ x1 += K1 + 3u;
  TFR(17) TFR(29) TFR(16) TFR(24)
  x0 += K1; x1 += K2 + 4u;
  TFR(13) TFR(15) TFR(26)
  x0 += x1;                              // round 20: only the add feeds o0
  x0 += K2;                              // final injection for o0
#undef TFR
  return x0;
}

DEVI uint32_t ld_dev_u32(const uint32_t* p) {
  return __hip_atomic_load(p, __ATOMIC_RELAXED, __HIP_MEMORY_SCOPE_AGENT);
}
DEVI void st_dev_u32(uint32_t* p, uint32_t v) {
  __hip_atomic_store(p, v, __ATOMIC_RELAXED, __HIP_MEMORY_SCOPE_AGENT);
}

// Raw-bits prune threshold: all j with g_j > m satisfy bits >= kb(m).
DEVI uint32_t prune_kb(float m) {
  float t = expf(-expf(-m)) - 1e-5f;
  if (!(t > 0.0f)) return 0u;
  uint32_t k = (uint32_t)ceilf(t * 8388608.0f);
  if (k > 8388607u) k = 8388607u;
  return k << 9;
}

// Exact JAX gumbel+logit value of element j of one sample.
DEVI float eval_v(uint32_t bits, uint32_t j,
                  const int* __restrict__ ids, const int* __restrict__ geto,
                  const float* __restrict__ probs, int D, int dlog) {
  float u = __uint_as_float((bits >> 9) | 0x3f800000u) - 1.0f;
  u = fmaxf(u, 1.17549435e-38f);
  float g = -logf(-logf(u));
  uint32_t b, d;
  if (dlog >= 0) { b = j >> dlog; d = j & (uint32_t)(D - 1); }
  else { b = j / (uint32_t)D; d = j - b * (uint32_t)D; }
  float lp = logf(probs[geto[(uint32_t)ids[b] * (uint32_t)D + d]]);
  return g + lp;
}

// ---- K0: phase A (max + first-argmax over j<D) ----------------------------
__global__ __launch_bounds__(64) void phasea_kernel(
    const int* __restrict__ ids, const int* __restrict__ geto,
    const float* __restrict__ probs,
    uint32_t* __restrict__ aidx, uint32_t* __restrict__ abits,
    uint32_t* __restrict__ kbv,
    int NC, int D, int dlog, uint32_t dcK) {
  const int s = blockIdx.x;
  const int lane = threadIdx.x;
  const uint32_t sbase = (uint32_t)s * (uint32_t)NC;

  float av = -INFINITY;
  int ai = INT_MAX;
  for (uint32_t j = (uint32_t)lane; j < (uint32_t)D; j += 64u) {
    uint32_t cc = sbase + j;
    float v = eval_v(tf_o0p(cc, cc + dcK), j, ids, geto, probs, D, dlog);
    if (v > av) { av = v; ai = (int)j; }   // ascending j: > keeps first
  }
  for (int off = 32; off > 0; off >>= 1) {
    float v2 = __shfl_xor(av, off);
    int i2 = __shfl_xor(ai, off);
    if (v2 > av || (v2 == av && i2 < ai)) { av = v2; ai = i2; }
  }
  if (lane == 0) {
    st_dev_u32(&aidx[s], (uint32_t)ai);
    st_dev_u32(&abits[s], __float_as_uint(av));
    st_dev_u32(&kbv[s], prune_kb(av));
  }
}

// ---- K1: per-wave-window witness scan, private result slot ----------------
__global__ __launch_bounds__(256) void witness_kernel(
    const int* __restrict__ ids, const int* __restrict__ geto,
    const float* __restrict__ probs,
    const uint32_t* __restrict__ abits, const uint32_t* __restrict__ kbv,
    uint32_t* __restrict__ wfound,
    int NC, int D, int dlog, uint32_t dcK, int wwin, int WV) {
  const int s = blockIdx.y;
  const int wv = blockIdx.x * 4 + (threadIdx.x >> 6);   // wave-window id
  const int lane = threadIdx.x & 63;
  if (wv >= WV) return;
  const uint32_t sbase = (uint32_t)s * (uint32_t)NC;

  const float A = __uint_as_float(ld_dev_u32(&abits[s]));
  const uint32_t kb = ld_dev_u32(&kbv[s]);

  uint32_t wstart = (uint32_t)D + (uint32_t)wv * (uint32_t)wwin;
  uint32_t wend = wstart + (uint32_t)wwin;
  if (wend > (uint32_t)NC) wend = (uint32_t)NC;

  bool wit = false;
  for (uint32_t base = wstart; base < wend && !wit; base += 512u) {
    uint32_t a[8];
    uint32_t bb = 0u, bj = 0xFFFFFFFFu;  // per-lane best passer
    bool anyok = false;
#pragma unroll
    for (int c = 0; c < 8; ++c) {
      uint32_t j = base + (uint32_t)(c * 64) + (uint32_t)lane;
      uint32_t cc = sbase + j;
      uint32_t bits = tf_o0p(cc, cc + dcK);
      a[c] = bits;
      bool ok = (bits >= kb) && (j < wend);
      if (ok) { anyok = true; if (bits > bb || bj == 0xFFFFFFFFu) { bb = bits; bj = j; } }
    }

    bool found = false;
    if (__any(anyok)) {
      // wave-reduce best candidate (max bits; index tie-break, deterministic)
      for (int off = 32; off > 0; off >>= 1) {
        uint32_t ob = __shfl_xor(bb, off);
        uint32_t oj = __shfl_xor(bj, off);
        bool better = (oj != 0xFFFFFFFFu) &&
                      (bj == 0xFFFFFFFFu || ob > bb || (ob == bb && oj < bj));
        if (better) { bb = ob; bj = oj; }
      }
      // Evaluate best candidate wave-uniform (broadcast loads, one chain).
      float v = eval_v(bb, bj, ids, geto, probs, D, dlog);
      if (v > A) {
        found = true;
      } else {
        // Rare fallback: evaluate every passer (exact round OR preserved).
#pragma unroll
        for (int c = 0; c < 8; ++c) {
          uint32_t j = base + (uint32_t)(c * 64) + (uint32_t)lane;
          if (a[c] >= kb && j < wend && j != bj) {
            if (eval_v(a[c], j, ids, geto, probs, D, dlog) > A) found = true;
          }
        }
      }
    }
    wit = __any(found);                  // wave-uniform
  }
  if (lane == 0)
    st_dev_u32(&wfound[(size_t)s * (size_t)WV + (size_t)wv], wit ? 1u : 0u);
}

// ---- K2: per-sample OR + select -------------------------------------------
__global__ __launch_bounds__(64) void reduce_kernel(
    const uint32_t* __restrict__ aidx, const uint32_t* __restrict__ wfound,
    uint32_t* __restrict__ ridx, int WV, int D) {
  const int s = blockIdx.x;
  uint32_t f = 0u;
  for (int t = threadIdx.x; t < WV; t += 64)
    f |= ld_dev_u32(&wfound[(size_t)s * (size_t)WV + (size_t)t]);
  bool any = __any(f != 0u);
  if (threadIdx.x == 0) {
    int r = any ? (D - 1) : (int)ld_dev_u32(&aidx[s]);
    r = r < 0 ? 0 : (r > D - 1 ? D - 1 : r);   // take(..., mode='clip')
    st_dev_u32(&ridx[s], (uint32_t)r);
  }
}

// ---- K3: gather outputs ----------------------------------------------------
__global__ __launch_bounds__(256) void gather_kernel(
    const int* __restrict__ ids, const int* __restrict__ adj,
    const int* __restrict__ geto, const uint32_t* __restrict__ ridx,
    int* __restrict__ out, int B, int D, int ns) {
  __shared__ int sr[64];
  if (threadIdx.x < ns) {
    int r = (int)ld_dev_u32(&ridx[threadIdx.x]);
    r = r < 0 ? 0 : (r > D - 1 ? D - 1 : r);   // defensive clamp
    sr[threadIdx.x] = r;
  }
  __syncthreads();
  int t = blockIdx.x * blockDim.x + threadIdx.x;
  int total = B * ns;
  if (t >= total) return;
  int b = t / ns;
  int s = t - b * ns;
  int r = sr[s];
  int row = ids[b];
  out[t] = adj[row * D + r];            // weighted_adj[:, :ns]
  out[total + t] = geto[row * D + r];   // weighted_geto[:, :ns]
}

// ---------------------------------------------------------------------------
extern "C" void kernel_launch(void* const* d_in, const int* in_sizes, int n_in,
                              void* d_out, int out_size, void* d_ws, size_t ws_size,
                              hipStream_t stream) {
  const int* ids = (const int*)d_in[0];
  const int* adj = (const int*)d_in[2];
  const int* geto = (const int*)d_in[3];
  const float* probs = (const float*)d_in[4];
  int* out = (int*)d_out;

  const int B = in_sizes[0];             // 100000
  const int D = in_sizes[2] / B;         // 64
  const int NC = B * D;                  // 6.4M categories
  const int S = D;                       // 64 total samples (RESAMPLING_RATE=0)
  const int ns = out_size / (2 * B);     // 25 — only these are consumed
  const uint32_t dc = (uint32_t)(S / 2) * (uint32_t)NC;  // classic-mode half
  const uint32_t dcK = dc + 42u;         // fold +K1 into the counter offset
  const int dlog = ((D & (D - 1)) == 0) ? __builtin_ctz(D) : -1;

  // 128 wave-windows per sample; 4 waves per 256-thread block.
  const int range = NC - D;
  int wwin = (range + 127) / 128;
  wwin = (wwin + 511) & ~511;            // multiple of one 512-elem round
  const int WV = (range + wwin - 1) / wwin;
  const int GX = (WV + 3) / 4;

  // ws layout: [aidx 64][abits 64][kbv 64][ridx 64][wfound ns*WV] u32
  uint32_t* aidx = (uint32_t*)d_ws;
  uint32_t* abits = aidx + 64;
  uint32_t* kbv = abits + 64;
  uint32_t* ridx = kbv + 64;
  uint32_t* wfound = ridx + 64;

  phasea_kernel<<<ns, 64, 0, stream>>>(ids, geto, probs, aidx, abits, kbv,
                                       NC, D, dlog, dcK);
  witness_kernel<<<dim3(GX, ns), 256, 0, stream>>>(ids, geto, probs, abits,
                                                   kbv, wfound, NC, D, dlog,
                                                   dcK, wwin, WV);
  reduce_kernel<<<ns, 64, 0, stream>>>(aidx, wfound, ridx, WV, D);
  int total = B * ns;
  gather_kernel<<<(total + 255) / 256, 256, 0, stream>>>(
      ids, adj, geto, ridx, out, B, D, ns);
}

// Round 9
// 47.088 us; speedup vs baseline: 3.1120x; 3.1120x over previous
//
#include <hip/hip_runtime.h>
#include <stdint.h>
#include <limits.h>

// ---------------------------------------------------------------------------
// GeToInformedNeighborSampler — round 9 (abort kept, contention removed).
//
// Exact clip-aware reduction (validated rounds 5-8, absmax 0):
//   A = max_{j<D} v_j, a = first argmax   (v_j = gumbel(s*NC+j) + logp[j])
//   r[s] = (exists j in [D,NC): v_j > A) ? D-1 : a
//
// Round-8 lesson: witness density is per-sample, spanning ~1.5e-2 .. ~1e-6.
// Without a cross-wave abort, the straggler sample's waves each scan their
// FULL window (~43us). With r7's abort but a shared RMW flag, the round-1
// flood of ~3k atomic_fetch_or into 1-2 lines serialized (~60us).
// This round: abort via per-sample flag on a PRIVATE 256B line, set with a
// plain AGENT store gated on the round's poll (poll==1 => flag already 1,
// monotonic => skip is exact), polled once per round (load issued at round
// start, consumed at round end). 256 wave-windows/sample => straggler finds
// its first witness in ~6 rounds (~2us) then everyone aborts.
//
// Flag determinism: flag is set only on a true witness; a wave aborts only
// when the flag is already 1 => final flag == [exists witness], exactly.
//
// RNG (threefry2x32 key (0,42), classic split, o0-only), raw-bits prune
// filter kb(A), best-candidate-first eval: unchanged (absmax 0, 7 rounds).
// All cross-kernel handoffs AGENT-scope (G16); flags re-zeroed every call
// by phasea (stream-ordered before witness) => graph-replay safe.
// ---------------------------------------------------------------------------

#define DEVI __device__ __forceinline__

DEVI uint32_t rotl32(uint32_t x, int n) { return (x << n) | (x >> (32 - n)); }

// threefry2x32-20, key (0,42), o0 only. x1 must already include +K1 (=42).
DEVI uint32_t tf_o0p(uint32_t x0, uint32_t x1) {
  const uint32_t K1 = 42u;
  const uint32_t K2 = 0x1BD11BDAu ^ K1;  // K0 = 0
#define TFR(r) x0 += x1; x1 = rotl32(x1, (r)); x1 ^= x0;
  TFR(13) TFR(15) TFR(26) TFR(6)
  x0 += K1; x1 += K2 + 1u;
  TFR(17) TFR(29) TFR(16) TFR(24)
  x0 += K2; x1 += 2u;                    // + K0 + 2
  TFR(13) TFR(15) TFR(26) TFR(6)
  /* x0 += K0 */ x1 += K1 + 3u;
  TFR(17) TFR(29) TFR(16) TFR(24)
  x0 += K1; x1 += K2 + 4u;
  TFR(13) TFR(15) TFR(26)
  x0 += x1;                              // round 20: only the add feeds o0
  x0 += K2;                              // final injection for o0
#undef TFR
  return x0;
}

DEVI uint32_t ld_dev_u32(const uint32_t* p) {
  return __hip_atomic_load(p, __ATOMIC_RELAXED, __HIP_MEMORY_SCOPE_AGENT);
}
DEVI void st_dev_u32(uint32_t* p, uint32_t v) {
  __hip_atomic_store(p, v, __ATOMIC_RELAXED, __HIP_MEMORY_SCOPE_AGENT);
}

// Raw-bits prune threshold: all j with g_j > m satisfy bits >= kb(m).
DEVI uint32_t prune_kb(float m) {
  float t = expf(-expf(-m)) - 1e-5f;
  if (!(t > 0.0f)) return 0u;
  uint32_t k = (uint32_t)ceilf(t * 8388608.0f);
  if (k > 8388607u) k = 8388607u;
  return k << 9;
}

// Exact JAX gumbel+logit value of element j of one sample.
DEVI float eval_v(uint32_t bits, uint32_t j,
                  const int* __restrict__ ids, const int* __restrict__ geto,
                  const float* __restrict__ probs, int D, int dlog) {
  float u = __uint_as_float((bits >> 9) | 0x3f800000u) - 1.0f;
  u = fmaxf(u, 1.17549435e-38f);
  float g = -logf(-logf(u));
  uint32_t b, d;
  if (dlog >= 0) { b = j >> dlog; d = j & (uint32_t)(D - 1); }
  else { b = j / (uint32_t)D; d = j - b * (uint32_t)D; }
  float lp = logf(probs[geto[(uint32_t)ids[b] * (uint32_t)D + d]]);
  return g + lp;
}

// ---- K0: phase A (max + first-argmax over j<D) + zero padded flag ---------
__global__ __launch_bounds__(64) void phasea_kernel(
    const int* __restrict__ ids, const int* __restrict__ geto,
    const float* __restrict__ probs,
    uint32_t* __restrict__ aidx, uint32_t* __restrict__ abits,
    uint32_t* __restrict__ kbv, uint32_t* __restrict__ wflag,
    int NC, int D, int dlog, uint32_t dcK) {
  const int s = blockIdx.x;
  const int lane = threadIdx.x;
  const uint32_t sbase = (uint32_t)s * (uint32_t)NC;

  float av = -INFINITY;
  int ai = INT_MAX;
  for (uint32_t j = (uint32_t)lane; j < (uint32_t)D; j += 64u) {
    uint32_t cc = sbase + j;
    float v = eval_v(tf_o0p(cc, cc + dcK), j, ids, geto, probs, D, dlog);
    if (v > av) { av = v; ai = (int)j; }   // ascending j: > keeps first
  }
  for (int off = 32; off > 0; off >>= 1) {
    float v2 = __shfl_xor(av, off);
    int i2 = __shfl_xor(ai, off);
    if (v2 > av || (v2 == av && i2 < ai)) { av = v2; ai = i2; }
  }
  if (lane == 0) {
    st_dev_u32(&aidx[s], (uint32_t)ai);
    st_dev_u32(&abits[s], __float_as_uint(av));
    st_dev_u32(&kbv[s], prune_kb(av));
    st_dev_u32(&wflag[s * 64], 0u);      // private 256B line, zeroed each call
  }
}

// ---- K1: per-wave-window witness scan with padded-flag abort --------------
__global__ __launch_bounds__(256) void witness_kernel(
    const int* __restrict__ ids, const int* __restrict__ geto,
    const float* __restrict__ probs,
    const uint32_t* __restrict__ abits, const uint32_t* __restrict__ kbv,
    uint32_t* __restrict__ wflag,
    int NC, int D, int dlog, uint32_t dcK, int wwin, int WV) {
  const int s = blockIdx.y;
  const int wv = blockIdx.x * 4 + (threadIdx.x >> 6);   // wave-window id
  const int lane = threadIdx.x & 63;
  if (wv >= WV) return;
  const uint32_t sbase = (uint32_t)s * (uint32_t)NC;
  uint32_t* flagp = &wflag[s * 64];

  const float A = __uint_as_float(ld_dev_u32(&abits[s]));
  const uint32_t kb = ld_dev_u32(&kbv[s]);

  uint32_t wstart = (uint32_t)D + (uint32_t)wv * (uint32_t)wwin;
  uint32_t wend = wstart + (uint32_t)wwin;
  if (wend > (uint32_t)NC) wend = (uint32_t)NC;

  for (uint32_t base = wstart; base < wend; base += 512u) {
    // Poll issued early (independent load), consumed at round end.
    uint32_t poll = 0u;
    if (lane == 0) poll = ld_dev_u32(flagp);

    uint32_t a[8];
    uint32_t bb = 0u, bj = 0xFFFFFFFFu;  // per-lane best passer
    bool anyok = false;
#pragma unroll
    for (int c = 0; c < 8; ++c) {
      uint32_t j = base + (uint32_t)(c * 64) + (uint32_t)lane;
      uint32_t cc = sbase + j;
      uint32_t bits = tf_o0p(cc, cc + dcK);
      a[c] = bits;
      bool ok = (bits >= kb) && (j < wend);
      if (ok) { anyok = true; if (bits > bb || bj == 0xFFFFFFFFu) { bb = bits; bj = j; } }
    }

    bool found = false;
    if (__any(anyok)) {
      // wave-reduce best candidate (max bits; index tie-break, deterministic)
      for (int off = 32; off > 0; off >>= 1) {
        uint32_t ob = __shfl_xor(bb, off);
        uint32_t oj = __shfl_xor(bj, off);
        bool better = (oj != 0xFFFFFFFFu) &&
                      (bj == 0xFFFFFFFFu || ob > bb || (ob == bb && oj < bj));
        if (better) { bb = ob; bj = oj; }
      }
      // Evaluate best candidate wave-uniform (broadcast loads, one chain).
      float v = eval_v(bb, bj, ids, geto, probs, D, dlog);
      if (v > A) {
        found = true;
      } else {
        // Rare fallback: evaluate every passer (exact round OR preserved).
#pragma unroll
        for (int c = 0; c < 8; ++c) {
          uint32_t j = base + (uint32_t)(c * 64) + (uint32_t)lane;
          if (a[c] >= kb && j < wend && j != bj) {
            if (eval_v(a[c], j, ids, geto, probs, D, dlog) > A) found = true;
          }
        }
      }
    }
    uint32_t p0 = (uint32_t)__shfl((int)poll, 0);
    if (__any(found)) {
      // plain agent store, gated: p0==1 => flag already 1 (monotonic), skip.
      if (lane == 0 && p0 == 0u) st_dev_u32(flagp, 1u);
      return;
    }
    if (p0) return;                      // someone already proved existence
  }
}

// ---- K2: select (one tiny block) ------------------------------------------
__global__ __launch_bounds__(64) void reduce_kernel(
    const uint32_t* __restrict__ aidx, const uint32_t* __restrict__ wflag,
    uint32_t* __restrict__ ridx, int D, int ns) {
  const int s = threadIdx.x;               // 64 lanes; slots [ns,64) unused
  uint32_t f = (s < ns) ? ld_dev_u32(&wflag[s * 64]) : 0u;
  int r = f ? (D - 1) : (int)ld_dev_u32(&aidx[s]);
  r = r < 0 ? 0 : (r > D - 1 ? D - 1 : r); // take(..., mode='clip')
  st_dev_u32(&ridx[s], (uint32_t)r);
}

// ---- K3: gather outputs ----------------------------------------------------
__global__ __launch_bounds__(256) void gather_kernel(
    const int* __restrict__ ids, const int* __restrict__ adj,
    const int* __restrict__ geto, const uint32_t* __restrict__ ridx,
    int* __restrict__ out, int B, int D, int ns) {
  __shared__ int sr[64];
  if (threadIdx.x < ns) {
    int r = (int)ld_dev_u32(&ridx[threadIdx.x]);
    r = r < 0 ? 0 : (r > D - 1 ? D - 1 : r);  // defensive clamp
    sr[threadIdx.x] = r;
  }
  __syncthreads();
  int t = blockIdx.x * blockDim.x + threadIdx.x;
  int total = B * ns;
  if (t >= total) return;
  int b = t / ns;
  int s = t - b * ns;
  int r = sr[s];
  int row = ids[b];
  out[t] = adj[row * D + r];            // weighted_adj[:, :ns]
  out[total + t] = geto[row * D + r];   // weighted_geto[:, :ns]
}

// ---------------------------------------------------------------------------
extern "C" void kernel_launch(void* const* d_in, const int* in_sizes, int n_in,
                              void* d_out, int out_size, void* d_ws, size_t ws_size,
                              hipStream_t stream) {
  const int* ids = (const int*)d_in[0];
  const int* adj = (const int*)d_in[2];
  const int* geto = (const int*)d_in[3];
  const float* probs = (const float*)d_in[4];
  int* out = (int*)d_out;

  const int B = in_sizes[0];             // 100000
  const int D = in_sizes[2] / B;         // 64
  const int NC = B * D;                  // 6.4M categories
  const int S = D;                       // 64 total samples (RESAMPLING_RATE=0)
  const int ns = out_size / (2 * B);     // 25 — only these are consumed
  const uint32_t dc = (uint32_t)(S / 2) * (uint32_t)NC;  // classic-mode half
  const uint32_t dcK = dc + 42u;         // fold +K1 into the counter offset
  const int dlog = ((D & (D - 1)) == 0) ? __builtin_ctz(D) : -1;

  // 256 wave-windows per sample; 4 waves per 256-thread block.
  const int range = NC - D;
  int wwin = (range + 255) / 256;
  wwin = (wwin + 511) & ~511;            // multiple of one 512-elem round
  const int WV = (range + wwin - 1) / wwin;
  const int GX = (WV + 3) / 4;

  // ws layout (u32): [aidx 64][abits 64][kbv 64][ridx 64][wflag ns*64 padded]
  uint32_t* aidx = (uint32_t*)d_ws;
  uint32_t* abits = aidx + 64;
  uint32_t* kbv = abits + 64;
  uint32_t* ridx = kbv + 64;
  uint32_t* wflag = ridx + 64;

  phasea_kernel<<<ns, 64, 0, stream>>>(ids, geto, probs, aidx, abits, kbv,
                                       wflag, NC, D, dlog, dcK);
  witness_kernel<<<dim3(GX, ns), 256, 0, stream>>>(ids, geto, probs, abits,
                                                   kbv, wflag, NC, D, dlog,
                                                   dcK, wwin, WV);
  reduce_kernel<<<1, 64, 0, stream>>>(aidx, wflag, ridx, D, ns);
  int total = B * ns;
  gather_kernel<<<(total + 255) / 256, 256, 0, stream>>>(
      ids, adj, geto, ridx, out, B, D, ns);
}